// Round 2
// baseline (706.823 us; speedup 1.0000x reference)
//
#include <hip/hip_runtime.h>
#include <hip/hip_bf16.h>

// DynamicMemoryBank: B=64, T=1024, C=256, M=1024 (T==M)
//   cat = [x, softmax(x@mem^T)@mem]           -> d_out[0 : 33554432]
//   gate = sigmoid(silu(cat@w1+b1)@w2+b2)
//   new_memory = mean_b(mem*(1-g) + xmean*g)  -> d_out[33554432 : +262144]
//
// R5 changes vs R4 (579 us, top GEMM 138 us, MfmaUtil 21.5%, VALUBusy 62%):
//   * B-stationary GEMM: B is tiny (<=1 MB) -> stage a [128][256-k] chunk of B
//     in LDS ONCE per 256-k; A (no intra-block reuse) streams global->register
//     directly as MFMA fragments (per-lane 16B loads). Kills the per-K-step
//     stage/drain/barrier rhythm entirely: zero barriers inside a k-chunk,
//     2 barriers per 256-k instead of 2 per 32-k.
//   * Template-K full unroll + manual depth-2 register prefetch of A and B
//     frags (static indices only, no scratch).

#define BT 65536    // B*T rows

typedef short bf16x8 __attribute__((ext_vector_type(8)));
typedef float f32x4 __attribute__((ext_vector_type(4)));

__device__ __forceinline__ unsigned short f2bf(float f) {
    unsigned x = __float_as_uint(f);
    unsigned r = (x + 0x7FFFu + ((x >> 16) & 1u)) >> 16;
    return (unsigned short)r;
}
__device__ __forceinline__ float bf2f(unsigned short u) {
    return __uint_as_float(((unsigned)u) << 16);
}

// async global->LDS, 16B per lane; hardware writes lane i at lds_base + i*16B.
__device__ __forceinline__ void async16(const unsigned short* g, unsigned short* l) {
    __builtin_amdgcn_global_load_lds((const __attribute__((address_space(1))) unsigned int*)g,
                                     (__attribute__((address_space(3))) unsigned int*)l,
                                     16, 0, 0);
}

// ---------------- prep kernels ----------------

// x -> d_out left half (fp32 copy) + cat_bf16 left half. 16384 blocks.
__global__ __launch_bounds__(256) void prep_x(const float* __restrict__ x,
                                              float* __restrict__ cat_out,
                                              unsigned short* __restrict__ cat_b) {
    long tid = (long)blockIdx.x * 256 + threadIdx.x;
    long i4 = tid * 4;
    long row = i4 >> 8;
    int c = (int)(i4 & 255);
    float4 v = *(const float4*)&x[i4];
    *(float4*)&cat_out[row * 512 + c] = v;
    ushort4 b4;
    b4.x = f2bf(v.x); b4.y = f2bf(v.y); b4.z = f2bf(v.z); b4.w = f2bf(v.w);
    *(ushort4*)&cat_b[row * 512 + c] = b4;
}

// memory -> mem_bf16 [m][c] and memT_bf16 [c][m]
__global__ __launch_bounds__(256) void prep_mem(const float* __restrict__ mem,
                                                unsigned short* __restrict__ mem_b,
                                                unsigned short* __restrict__ memT_b) {
    int tid = blockIdx.x * 256 + threadIdx.x;  // 262144
    mem_b[tid] = f2bf(mem[tid]);
    int c = tid >> 10, m = tid & 1023;
    memT_b[tid] = f2bf(mem[m * 256 + c]);
}

// w1[512k][1024f] -> w1T[1024f][512k]
__global__ __launch_bounds__(256) void prep_w1(const float* __restrict__ w1,
                                               unsigned short* __restrict__ w1T) {
    int tid = blockIdx.x * 256 + threadIdx.x;  // 524288
    int f = tid >> 9, k = tid & 511;
    w1T[tid] = f2bf(w1[k * 1024 + f]);
}

// w2[1024k][256c] -> w2T[256c][1024k]
__global__ __launch_bounds__(256) void prep_w2(const float* __restrict__ w2,
                                               unsigned short* __restrict__ w2T) {
    int tid = blockIdx.x * 256 + threadIdx.x;  // 262144
    int c = tid >> 10, k = tid & 1023;
    w2T[tid] = f2bf(w2[k * 256 + c]);
}

// xmean[b][c] = mean_t x[b,t,c]  (xmean zeroed via hipMemsetAsync first)
__global__ __launch_bounds__(256) void xmean_k(const float* __restrict__ x,
                                               float* __restrict__ xmean) {
    int b = blockIdx.x;
    int t0 = blockIdx.y * 64;
    int c = threadIdx.x;
    float s = 0.f;
    for (int t = 0; t < 64; t++)
        s += x[((long)(b * 1024 + t0 + t)) * 256 + c];
    atomicAdd(&xmean[b * 256 + c], s * (1.f / 1024.f));
}

// ---------------- B-stationary bf16 MFMA GEMM ----------------
// C[M x N] = A[M x K] * Bt[N x K]^T, bf16, fp32 accum.
// BM=BN=128. 256 threads = 4 waves 2x2, each wave 64x64 of C.
// B k-chunk [128][256] (64 KB) staged in LDS (XOR-swizzled source so frag
// ds_read_b128 spreads uniformly over banks); A streamed global->register
// as MFMA fragments (per-lane 16B, no LDS). No barriers within a chunk.
// Frag layouts (verified m89/m91): A[m=l16][k=quad*8+j], B[n=l16][k=quad*8+j],
// C/D row=quad*4+reg, col=l16.
// MODE 0: energy -> bf16 (ld 1024)       MODE 1: retrieved -> fp32+bf16 cat
// MODE 2: silu(acc+b1) -> bf16 (ld 1024) MODE 3: sigmoid(acc+b2) -> fp32 (ld 256)
template <int MODE, int K>
__global__ __launch_bounds__(256) void gemm_bt(const unsigned short* __restrict__ A,
                                               const unsigned short* __restrict__ Bt,
                                               float* __restrict__ outF,
                                               unsigned short* __restrict__ outB,
                                               const float* __restrict__ bias) {
    constexpr int LDA = (MODE == 0 || MODE == 2) ? 512 : 1024;
    constexpr int NC = K / 256;                     // 256-wide k-chunks
    const int t = threadIdx.x;
    const int wave = t >> 6, lane = t & 63;
    const int waveM = wave >> 1, waveN = wave & 1;
    const int quad = lane >> 4, l16 = lane & 15;

    // XCD-bijective chunk swizzle (all grids have nwg % 8 == 0): each XCD gets
    // a contiguous m-range for all n -> A-panel fetched by one XCD, shared in L2.
    const int nwg = gridDim.x * gridDim.y;
    const int lid = blockIdx.y * gridDim.x + blockIdx.x;
    const int sid = (lid & 7) * (nwg >> 3) + (lid >> 3);
    const int nb = sid % gridDim.x;
    const int mb = sid / gridDim.x;
    const long n0 = (long)nb * 128;
    const long m0 = (long)mb * 128;

    __shared__ unsigned short lB[128 * 256];        // 64 KB: B rows x 256 k

    f32x4 acc[4][4] = {};

    // ---- B staging geometry ----
    // stage call j: wave writes rows [j*8+wave*2, +2) linearly; lane covers
    // (row = +lane/32, slot = lane&31). LDS slot s of row r holds global
    // chunk s^(r&7)  (r&7 == rw below, j*8 keeps low bits).
    const int rw = wave * 2 + (lane >> 5);          // 0..7 = r & 7
    const int sc = lane & 31;                       // slot this lane fills
    const unsigned short* Bg = Bt + (n0 + rw) * (long)K + (long)((sc ^ rw) * 8);

#define STAGE_B(CH) do {                                                   \
        _Pragma("unroll")                                                  \
        for (int j = 0; j < 16; j++)                                       \
            async16(Bg + (long)j * (8 * K) + (CH) * 256,                   \
                    &lB[j * 2048 + wave * 512]);                           \
    } while (0)

    // ---- A stream pointers (per-lane, 4 row-frags = the MFMA A layout) ----
    const unsigned short* Ap[4];
#pragma unroll
    for (int i = 0; i < 4; i++)
        Ap[i] = A + (m0 + waveM * 64 + i * 16 + l16) * (long)LDA + quad * 8;

    // ---- B frag read offsets: row part + dynamic swizzled slot ----
    const int bx = l16 & 7;
    int brow[4];
#pragma unroll
    for (int j = 0; j < 4; j++)
        brow[j] = (waveN * 64 + j * 16 + l16) * 256;

    STAGE_B(0);
    asm volatile("s_waitcnt vmcnt(0)" ::: "memory");
    __builtin_amdgcn_s_barrier();
    __builtin_amdgcn_sched_barrier(0);

#pragma unroll
    for (int c = 0; c < NC; ++c) {
        const int kb = c * 256;
        bf16x8 af[2][4], bfr[2][4];
        // prefetch kk=0 (static indices only)
#pragma unroll
        for (int i = 0; i < 4; i++) af[0][i] = *(const bf16x8*)(Ap[i] + kb);
#pragma unroll
        for (int j = 0; j < 4; j++) bfr[0][j] = *(const bf16x8*)&lB[brow[j] + ((quad ^ bx) * 8)];
#pragma unroll
        for (int kk = 0; kk < 8; ++kk) {
            const int cur = kk & 1, nxt = cur ^ 1;
            if (kk < 7) {
#pragma unroll
                for (int i = 0; i < 4; i++)
                    af[nxt][i] = *(const bf16x8*)(Ap[i] + kb + (kk + 1) * 32);
#pragma unroll
                for (int j = 0; j < 4; j++)
                    bfr[nxt][j] = *(const bf16x8*)&lB[brow[j] + ((((kk + 1) * 4 + quad) ^ bx) * 8)];
            }
#pragma unroll
            for (int i = 0; i < 4; i++)
#pragma unroll
                for (int j = 0; j < 4; j++)
                    acc[i][j] = __builtin_amdgcn_mfma_f32_16x16x32_bf16(af[cur][i], bfr[cur][j], acc[i][j], 0, 0, 0);
        }
        if (c + 1 < NC) {
            // in-flight ds_reads must complete before anyone's DMA clobbers lB
            asm volatile("s_waitcnt lgkmcnt(0)" ::: "memory");
            __builtin_amdgcn_sched_barrier(0);
            __builtin_amdgcn_s_barrier();           // all waves done reading
            STAGE_B(c + 1);
            asm volatile("s_waitcnt vmcnt(0)" ::: "memory");
            __builtin_amdgcn_s_barrier();           // chunk staged everywhere
            __builtin_amdgcn_sched_barrier(0);
        }
    }
#undef STAGE_B

#pragma unroll
    for (int i = 0; i < 4; i++) {
#pragma unroll
        for (int j = 0; j < 4; j++) {
            long col = n0 + waveN * 64 + j * 16 + l16;
            float bval = (MODE == 2 || MODE == 3) ? bias[col] : 0.f;
#pragma unroll
            for (int r = 0; r < 4; r++) {
                long row = m0 + waveM * 64 + i * 16 + quad * 4 + r;
                float v = acc[i][j][r];
                if (MODE == 0) {
                    outB[row * 1024 + col] = f2bf(v);
                } else if (MODE == 1) {
                    long o = row * 512 + 256 + col;
                    outF[o] = v;
                    outB[o] = f2bf(v);
                } else if (MODE == 2) {
                    float z = v + bval;
                    float s = 1.f / (1.f + __expf(-z));
                    outB[row * 1024 + col] = f2bf(z * s);   // silu
                } else {
                    float z = v + bval;
                    outF[row * 256 + col] = 1.f / (1.f + __expf(-z));  // sigmoid
                }
            }
        }
    }
}

// ---------------- row softmax over M=1024, in place on bf16 P ----------------
__global__ __launch_bounds__(256) void softmax_rows(unsigned short* __restrict__ P) {
    long row = (long)blockIdx.x * 4 + (threadIdx.x >> 6);
    int lane = threadIdx.x & 63;
    unsigned short* p = P + row * 1024 + lane * 16;
    uint4 u0 = *(const uint4*)p;
    uint4 u1 = *(const uint4*)(p + 8);
    const unsigned short* ua = (const unsigned short*)&u0;
    const unsigned short* ub = (const unsigned short*)&u1;
    float v[16];
#pragma unroll
    for (int i = 0; i < 8; i++) { v[i] = bf2f(ua[i]); v[i + 8] = bf2f(ub[i]); }
    float m = -1e30f;
#pragma unroll
    for (int i = 0; i < 16; i++) m = fmaxf(m, v[i]);
    for (int off = 32; off >= 1; off >>= 1) m = fmaxf(m, __shfl_xor(m, off));
    float s = 0.f;
#pragma unroll
    for (int i = 0; i < 16; i++) { v[i] = __expf(v[i] - m); s += v[i]; }
    for (int off = 32; off >= 1; off >>= 1) s += __shfl_xor(s, off);
    float inv = 1.f / s;
    unsigned short o[16];
#pragma unroll
    for (int i = 0; i < 16; i++) o[i] = f2bf(v[i] * inv);
    *(uint4*)p = *(uint4*)&o[0];
    *(uint4*)(p + 8) = *(uint4*)&o[8];
}

// ---------------- final memory blend + batch mean ----------------
// new_memory[m,c] = mem[m,c] + (1/64) * sum_b gate[b,m,c]*(xmean[b,c]-mem[m,c])
__global__ __launch_bounds__(256) void reduce_mem(const float* __restrict__ gate,
                                                  const float* __restrict__ memory,
                                                  const float* __restrict__ xmean,
                                                  float* __restrict__ out2) {
    int m = blockIdx.x, c = threadIdx.x;
    float mm = memory[m * 256 + c];
    float s = 0.f;
    for (int b = 0; b < 64; b++)
        s += gate[((long)(b * 1024 + m)) * 256 + c] * (xmean[b * 256 + c] - mm);
    out2[m * 256 + c] = mm + s * (1.f / 64.f);
}

extern "C" void kernel_launch(void* const* d_in, const int* in_sizes, int n_in,
                              void* d_out, int out_size, void* d_ws, size_t ws_size,
                              hipStream_t stream) {
    const float* x      = (const float*)d_in[0];
    const float* memory = (const float*)d_in[1];
    const float* w1     = (const float*)d_in[2];
    const float* b1     = (const float*)d_in[3];
    const float* w2     = (const float*)d_in[4];
    const float* b2     = (const float*)d_in[5];
    float* out = (float*)d_out;

    // workspace carve (all 16B aligned); peak ~194.6 MiB
    unsigned short* mem_b  = (unsigned short*)d_ws;            // 262144 el
    unsigned short* memT_b = mem_b + 262144;                   // 262144 el
    unsigned short* w1T    = memT_b + 262144;                  // 524288 el
    unsigned short* w2T    = w1T + 524288;                     // 262144 el
    float* xmean           = (float*)(w2T + 262144);           // 16384 el
    unsigned short* cat_b  = (unsigned short*)(xmean + 16384); // BT x 512
    unsigned short* Pbuf   = cat_b + 33554432;                 // BT x 1024; reused as h
    float* gate            = (float*)cat_b;                    // aliases cat_b (dead after GEMM2)

    hipMemsetAsync(xmean, 0, 64 * 256 * sizeof(float), stream);

    prep_mem<<<1024, 256, 0, stream>>>(memory, mem_b, memT_b);
    prep_w1<<<2048, 256, 0, stream>>>(w1, w1T);
    prep_w2<<<1024, 256, 0, stream>>>(w2, w2T);
    prep_x<<<16384, 256, 0, stream>>>(x, out, cat_b);
    xmean_k<<<dim3(64, 16), 256, 0, stream>>>(x, xmean);

    // energy = x @ mem^T : A=cat_b left half (LDA=512, K=256), Bt=mem_b[1024][256]
    gemm_bt<0, 256><<<dim3(8, 512), 256, 0, stream>>>(cat_b, mem_b, nullptr, Pbuf, nullptr);
    softmax_rows<<<16384, 256, 0, stream>>>(Pbuf);
    // retrieved = P @ mem : A=Pbuf (LDA=1024, K=1024), Bt=memT[256][1024]
    gemm_bt<1, 1024><<<dim3(2, 512), 256, 0, stream>>>(Pbuf, memT_b, out, cat_b, nullptr);
    // h = silu(cat@w1+b1) : A=cat_b (LDA=512, K=512), Bt=w1T[1024][512]
    gemm_bt<2, 512><<<dim3(8, 512), 256, 0, stream>>>(cat_b, w1T, nullptr, Pbuf, b1);
    // gate = sigmoid(h@w2+b2) : A=Pbuf/h (LDA=1024, K=1024), Bt=w2T[256][1024]
    gemm_bt<3, 1024><<<dim3(2, 512), 256, 0, stream>>>(Pbuf, w2T, gate, nullptr, b2);

    reduce_mem<<<1024, 256, 0, stream>>>(gate, memory, xmean, out + 33554432);
}

// Round 3
// 550.897 us; speedup vs baseline: 1.2830x; 1.2830x over previous
//
#include <hip/hip_runtime.h>
#include <hip/hip_bf16.h>

// DynamicMemoryBank: B=64, T=1024, C=256, M=1024 (T==M)
//   cat = [x, softmax(x@mem^T)@mem]           -> d_out[0 : 33554432]
//   gate = sigmoid(silu(cat@w1+b1)@w2+b2)
//   new_memory = mean_b(mem*(1-g) + xmean*g)  -> d_out[33554432 : +262144]
//
// R6: revert R5's A-streaming (regressed 579->707: depth-2 reg prefetch can't
// cover global latency at 2 blocks/CU; [128][256] LDS tile had 4.2M bank
// conflicts). Back to R4's global_load_lds skeleton (579 us, MfmaUtil 21.5%)
// with the T4 fix for its remaining stall:
//   * TRIPLE-buffered LDS (48 KB) + counted vmcnt(4): stage tile k+2 each
//     step, wait only for tile k+1 (issued a full step earlier, ~400+ cy
//     elapsed -> stall ~0). DMAs stay in flight ACROSS barriers; never
//     drain to 0 in the loop (AITER discipline).
//   * lgkmcnt(0) before each barrier: all waves' ds_reads of the buffer
//     about to be clobbered (read 2 steps ago) are provably complete.

#define BT 65536    // B*T rows

typedef short bf16x8 __attribute__((ext_vector_type(8)));
typedef float f32x4 __attribute__((ext_vector_type(4)));

__device__ __forceinline__ unsigned short f2bf(float f) {
    unsigned x = __float_as_uint(f);
    unsigned r = (x + 0x7FFFu + ((x >> 16) & 1u)) >> 16;
    return (unsigned short)r;
}
__device__ __forceinline__ float bf2f(unsigned short u) {
    return __uint_as_float(((unsigned)u) << 16);
}

// async global->LDS, 16B per lane; hardware writes lane i at lds_base + i*16B.
__device__ __forceinline__ void async16(const unsigned short* g, unsigned short* l) {
    __builtin_amdgcn_global_load_lds((const __attribute__((address_space(1))) unsigned int*)g,
                                     (__attribute__((address_space(3))) unsigned int*)l,
                                     16, 0, 0);
}

// ---------------- prep kernels ----------------

// x -> d_out left half (fp32 copy) + cat_bf16 left half. 16384 blocks.
__global__ __launch_bounds__(256) void prep_x(const float* __restrict__ x,
                                              float* __restrict__ cat_out,
                                              unsigned short* __restrict__ cat_b) {
    long tid = (long)blockIdx.x * 256 + threadIdx.x;
    long i4 = tid * 4;
    long row = i4 >> 8;
    int c = (int)(i4 & 255);
    float4 v = *(const float4*)&x[i4];
    *(float4*)&cat_out[row * 512 + c] = v;
    ushort4 b4;
    b4.x = f2bf(v.x); b4.y = f2bf(v.y); b4.z = f2bf(v.z); b4.w = f2bf(v.w);
    *(ushort4*)&cat_b[row * 512 + c] = b4;
}

// memory -> mem_bf16 [m][c] and memT_bf16 [c][m]
__global__ __launch_bounds__(256) void prep_mem(const float* __restrict__ mem,
                                                unsigned short* __restrict__ mem_b,
                                                unsigned short* __restrict__ memT_b) {
    int tid = blockIdx.x * 256 + threadIdx.x;  // 262144
    mem_b[tid] = f2bf(mem[tid]);
    int c = tid >> 10, m = tid & 1023;
    memT_b[tid] = f2bf(mem[m * 256 + c]);
}

// w1[512k][1024f] -> w1T[1024f][512k]
__global__ __launch_bounds__(256) void prep_w1(const float* __restrict__ w1,
                                               unsigned short* __restrict__ w1T) {
    int tid = blockIdx.x * 256 + threadIdx.x;  // 524288
    int f = tid >> 9, k = tid & 511;
    w1T[tid] = f2bf(w1[k * 1024 + f]);
}

// w2[1024k][256c] -> w2T[256c][1024k]
__global__ __launch_bounds__(256) void prep_w2(const float* __restrict__ w2,
                                               unsigned short* __restrict__ w2T) {
    int tid = blockIdx.x * 256 + threadIdx.x;  // 262144
    int c = tid >> 10, k = tid & 1023;
    w2T[tid] = f2bf(w2[k * 256 + c]);
}

// xmean[b][c] = mean_t x[b,t,c]  (xmean zeroed via hipMemsetAsync first)
__global__ __launch_bounds__(256) void xmean_k(const float* __restrict__ x,
                                               float* __restrict__ xmean) {
    int b = blockIdx.x;
    int t0 = blockIdx.y * 64;
    int c = threadIdx.x;
    float s = 0.f;
    for (int t = 0; t < 64; t++)
        s += x[((long)(b * 1024 + t0 + t)) * 256 + c];
    atomicAdd(&xmean[b * 256 + c], s * (1.f / 1024.f));
}

// ---------------- templated bf16 MFMA GEMM (3-stage pipelined) ----------------
// C[M x N] = A[M x K] * Bt[N x K]^T, bf16, fp32 accum.
// BM=BN=128, BK=32. 256 threads = 4 waves 2x2, each wave 64x64 of C.
// Triple-buffered LDS (48 KB); K-loop per step kt:
//   STAGE(kt+2) -> ds_read+MFMA(kt) -> vmcnt(4) lgkmcnt(0) -> s_barrier
// vmcnt(4) waits only for tile kt+1 (issued one full step earlier); tile
// kt+2's 4 DMAs stay in flight across the barrier. lgkmcnt(0)+barrier
// guarantees all waves finished reading buf[(kt+2)%3] (== buf[(kt-1)%3])
// before the next step's STAGE clobbers it.
// Frag layouts (verified m89/m91): A[m=l16][k=quad*8+j], B[n=l16][k=quad*8+j],
// C/D row=quad*4+reg, col=l16. Source chunks XOR-swizzled so frag ds_read_b128
// is 2-way (free; R4 measured 0 conflicts).
// MODE 0: energy -> bf16 (ld 1024)       MODE 1: retrieved -> fp32+bf16 cat
// MODE 2: silu(acc+b1) -> bf16 (ld 1024) MODE 3: sigmoid(acc+b2) -> fp32 (ld 256)

__device__ __forceinline__ void compute_tile(const unsigned short* bufA,
                                             const unsigned short* bufB,
                                             const int* aoff, const int* boff,
                                             f32x4 acc[4][4]) {
    bf16x8 af[4], bfr[4];
#pragma unroll
    for (int i = 0; i < 4; i++) af[i] = *(const bf16x8*)&bufA[aoff[i]];
#pragma unroll
    for (int j = 0; j < 4; j++) bfr[j] = *(const bf16x8*)&bufB[boff[j]];
#pragma unroll
    for (int i = 0; i < 4; i++)
#pragma unroll
        for (int j = 0; j < 4; j++)
            acc[i][j] = __builtin_amdgcn_mfma_f32_16x16x32_bf16(af[i], bfr[j], acc[i][j], 0, 0, 0);
}

template <int MODE, int K>
__global__ __launch_bounds__(256) void gemm_bt(const unsigned short* __restrict__ A,
                                               const unsigned short* __restrict__ Bt,
                                               float* __restrict__ outF,
                                               unsigned short* __restrict__ outB,
                                               const float* __restrict__ bias) {
    constexpr long LDA = (MODE == 0 || MODE == 2) ? 512 : 1024;
    constexpr int NK = K / 32;          // 8 / 32 / 16 / 32 k-steps
    const int t = threadIdx.x;
    const int wave = t >> 6, lane = t & 63;
    const int waveM = wave >> 1, waveN = wave & 1;
    const int quad = lane >> 4, l16 = lane & 15;

    // XCD-bijective chunk swizzle (all grids have nwg % 8 == 0): each XCD gets
    // a contiguous m-range for all n -> A-panel fetched by one XCD, shared in
    // its L2 (R4: FETCH 266 MB -> 42 MB).
    const int nwg = gridDim.x * gridDim.y;
    const int lid = blockIdx.y * gridDim.x + blockIdx.x;
    const int sid = (lid & 7) * (nwg >> 3) + (lid >> 3);
    const int nb = sid % gridDim.x;
    const int mb = sid / gridDim.x;
    const long n0 = (long)nb * 128;
    const long m0 = (long)mb * 128;

    __shared__ unsigned short lA[3][128 * 32];
    __shared__ unsigned short lB[3][128 * 32];

    f32x4 acc[4][4] = {};

    // staging: wave w covers rows [w*16, w*16+16) (call 0) and +64 (call 1)
    const int sRow = wave * 16 + (lane >> 2);            // 0..63
    const int sC = (lane & 3) ^ ((sRow >> 1) & 3);       // swizzled source chunk
    const unsigned short* Ag0 = A + (m0 + sRow) * LDA + sC * 8;
    const unsigned short* Ag1 = Ag0 + 64 * LDA;
    const unsigned short* Bg0 = Bt + (n0 + sRow) * (long)K + sC * 8;
    const unsigned short* Bg1 = Bg0 + 64 * (long)K;
    const int so0 = wave * 512;           // shorts offset within one buffer
    const int so1 = 2048 + wave * 512;

    // frag LDS offsets (shorts), precomputed; chunk q lives at slot q^((r>>1)&3)
    const int sx = (l16 >> 1) & 3;
    int aoff[4], boff[4];
#pragma unroll
    for (int i = 0; i < 4; i++) {
        aoff[i] = (waveM * 64 + i * 16 + l16) * 32 + ((quad ^ sx) * 8);
        boff[i] = (waveN * 64 + i * 16 + l16) * 32 + ((quad ^ sx) * 8);
    }

#define STAGE(BUF, KT) do {                                   \
        async16(Ag0 + (KT) * 32, &lA[BUF][so0]);              \
        async16(Ag1 + (KT) * 32, &lA[BUF][so1]);              \
        async16(Bg0 + (KT) * 32, &lB[BUF][so0]);              \
        async16(Bg1 + (KT) * 32, &lB[BUF][so1]);              \
    } while (0)

    // prologue: tiles 0 and 1 in flight; wait only for tile 0 (vmcnt(4)).
    STAGE(0, 0);
    STAGE(1, 1);
    asm volatile("s_waitcnt vmcnt(4)" ::: "memory");
    __builtin_amdgcn_s_barrier();
    __builtin_amdgcn_sched_barrier(0);

#pragma unroll
    for (int kt = 0; kt < NK; ++kt) {
        if (kt + 2 < NK) {
            STAGE((kt + 2) % 3, kt + 2);
            __builtin_amdgcn_sched_barrier(0);   // keep DMA issue ahead of compute
        }
        compute_tile(&lA[kt % 3][0], &lB[kt % 3][0], aoff, boff, acc);
        if (kt + 2 < NK) {
            // tile kt+1 done (its 4 DMAs are the oldest; kt+2's 4 stay in flight);
            // lgkmcnt(0): my ds_reads of buf[(kt-1)%3] complete before barrier.
            asm volatile("s_waitcnt vmcnt(4) lgkmcnt(0)" ::: "memory");
            __builtin_amdgcn_s_barrier();
            __builtin_amdgcn_sched_barrier(0);
        } else if (kt + 1 < NK) {
            asm volatile("s_waitcnt vmcnt(0) lgkmcnt(0)" ::: "memory");
            __builtin_amdgcn_s_barrier();
            __builtin_amdgcn_sched_barrier(0);
        }
    }
#undef STAGE

#pragma unroll
    for (int i = 0; i < 4; i++) {
#pragma unroll
        for (int j = 0; j < 4; j++) {
            long col = n0 + waveN * 64 + j * 16 + l16;
            float bval = (MODE == 2 || MODE == 3) ? bias[col] : 0.f;
#pragma unroll
            for (int r = 0; r < 4; r++) {
                long row = m0 + waveM * 64 + i * 16 + quad * 4 + r;
                float v = acc[i][j][r];
                if (MODE == 0) {
                    outB[row * 1024 + col] = f2bf(v);
                } else if (MODE == 1) {
                    long o = row * 512 + 256 + col;
                    outF[o] = v;
                    outB[o] = f2bf(v);
                } else if (MODE == 2) {
                    float z = v + bval;
                    float s = 1.f / (1.f + __expf(-z));
                    outB[row * 1024 + col] = f2bf(z * s);   // silu
                } else {
                    float z = v + bval;
                    outF[row * 256 + col] = 1.f / (1.f + __expf(-z));  // sigmoid
                }
            }
        }
    }
}

// ---------------- row softmax over M=1024, in place on bf16 P ----------------
__global__ __launch_bounds__(256) void softmax_rows(unsigned short* __restrict__ P) {
    long row = (long)blockIdx.x * 4 + (threadIdx.x >> 6);
    int lane = threadIdx.x & 63;
    unsigned short* p = P + row * 1024 + lane * 16;
    uint4 u0 = *(const uint4*)p;
    uint4 u1 = *(const uint4*)(p + 8);
    const unsigned short* ua = (const unsigned short*)&u0;
    const unsigned short* ub = (const unsigned short*)&u1;
    float v[16];
#pragma unroll
    for (int i = 0; i < 8; i++) { v[i] = bf2f(ua[i]); v[i + 8] = bf2f(ub[i]); }
    float m = -1e30f;
#pragma unroll
    for (int i = 0; i < 16; i++) m = fmaxf(m, v[i]);
    for (int off = 32; off >= 1; off >>= 1) m = fmaxf(m, __shfl_xor(m, off));
    float s = 0.f;
#pragma unroll
    for (int i = 0; i < 16; i++) { v[i] = __expf(v[i] - m); s += v[i]; }
    for (int off = 32; off >= 1; off >>= 1) s += __shfl_xor(s, off);
    float inv = 1.f / s;
    unsigned short o[16];
#pragma unroll
    for (int i = 0; i < 16; i++) o[i] = f2bf(v[i] * inv);
    *(uint4*)p = *(uint4*)&o[0];
    *(uint4*)(p + 8) = *(uint4*)&o[8];
}

// ---------------- final memory blend + batch mean ----------------
// new_memory[m,c] = mem[m,c] + (1/64) * sum_b gate[b,m,c]*(xmean[b,c]-mem[m,c])
__global__ __launch_bounds__(256) void reduce_mem(const float* __restrict__ gate,
                                                  const float* __restrict__ memory,
                                                  const float* __restrict__ xmean,
                                                  float* __restrict__ out2) {
    int m = blockIdx.x, c = threadIdx.x;
    float mm = memory[m * 256 + c];
    float s = 0.f;
    for (int b = 0; b < 64; b++)
        s += gate[((long)(b * 1024 + m)) * 256 + c] * (xmean[b * 256 + c] - mm);
    out2[m * 256 + c] = mm + s * (1.f / 64.f);
}

extern "C" void kernel_launch(void* const* d_in, const int* in_sizes, int n_in,
                              void* d_out, int out_size, void* d_ws, size_t ws_size,
                              hipStream_t stream) {
    const float* x      = (const float*)d_in[0];
    const float* memory = (const float*)d_in[1];
    const float* w1     = (const float*)d_in[2];
    const float* b1     = (const float*)d_in[3];
    const float* w2     = (const float*)d_in[4];
    const float* b2     = (const float*)d_in[5];
    float* out = (float*)d_out;

    // workspace carve (all 16B aligned); peak ~194.6 MiB
    unsigned short* mem_b  = (unsigned short*)d_ws;            // 262144 el
    unsigned short* memT_b = mem_b + 262144;                   // 262144 el
    unsigned short* w1T    = memT_b + 262144;                  // 524288 el
    unsigned short* w2T    = w1T + 524288;                     // 262144 el
    float* xmean           = (float*)(w2T + 262144);           // 16384 el
    unsigned short* cat_b  = (unsigned short*)(xmean + 16384); // BT x 512
    unsigned short* Pbuf   = cat_b + 33554432;                 // BT x 1024; reused as h
    float* gate            = (float*)cat_b;                    // aliases cat_b (dead after GEMM2)

    hipMemsetAsync(xmean, 0, 64 * 256 * sizeof(float), stream);

    prep_mem<<<1024, 256, 0, stream>>>(memory, mem_b, memT_b);
    prep_w1<<<2048, 256, 0, stream>>>(w1, w1T);
    prep_w2<<<1024, 256, 0, stream>>>(w2, w2T);
    prep_x<<<16384, 256, 0, stream>>>(x, out, cat_b);
    xmean_k<<<dim3(64, 16), 256, 0, stream>>>(x, xmean);

    // energy = x @ mem^T : A=cat_b left half (LDA=512, K=256), Bt=mem_b[1024][256]
    gemm_bt<0, 256><<<dim3(8, 512), 256, 0, stream>>>(cat_b, mem_b, nullptr, Pbuf, nullptr);
    softmax_rows<<<16384, 256, 0, stream>>>(Pbuf);
    // retrieved = P @ mem : A=Pbuf (LDA=1024, K=1024), Bt=memT[256][1024]
    gemm_bt<1, 1024><<<dim3(2, 512), 256, 0, stream>>>(Pbuf, memT_b, out, cat_b, nullptr);
    // h = silu(cat@w1+b1) : A=cat_b (LDA=512, K=512), Bt=w1T[1024][512]
    gemm_bt<2, 512><<<dim3(8, 512), 256, 0, stream>>>(cat_b, w1T, nullptr, Pbuf, b1);
    // gate = sigmoid(h@w2+b2) : A=Pbuf/h (LDA=1024, K=1024), Bt=w2T[256][1024]
    gemm_bt<3, 1024><<<dim3(2, 512), 256, 0, stream>>>(Pbuf, w2T, gate, nullptr, b2);

    reduce_mem<<<1024, 256, 0, stream>>>(gate, memory, xmean, out + 33554432);
}